// Round 5
// baseline (291.660 us; speedup 1.0000x reference)
//
#include <hip/hip_runtime.h>

// ---------------------------------------------------------------------------
// MHA (GQA + RoPE, non-causal) on MI355X, bf16 MFMA pipeline, fp32 in/out.
// B=2 S=2048 D=2048 H=16 KV=4 hd=128.
// R5: attention — V read direct from global (no LDS staging; L1/L2-resident,
//     loads issued under softmax), ONE barrier per iter (stage->compute->sync),
//     v_cvt_pk_bf16_f32 for P packing. K stays LDS double-buffered.
// ---------------------------------------------------------------------------

typedef __attribute__((ext_vector_type(8))) short short8;
typedef __attribute__((ext_vector_type(4))) float f32x4;

#define DEV static __device__ __forceinline__

#define NB 2
#define NS 2048
#define ND 2048
#define NH 16
#define NKV 4
#define HD 128
#define NQKV 3072   // H*hd + 2*KV*hd

DEV unsigned short f2bf(float f) {
  union { float f; unsigned u; } v; v.f = f;
  unsigned r = v.u + 0x7fffu + ((v.u >> 16) & 1u);   // RNE
  return (unsigned short)(r >> 16);
}
DEV float bf2f(unsigned short u) {
  union { unsigned u; float f; } v; v.u = ((unsigned)u) << 16; return v.f;
}
DEV unsigned pack2bf_rne(float a, float b) {
  return (unsigned)f2bf(a) | ((unsigned)f2bf(b) << 16);
}
DEV unsigned cvtpk(float a, float b) {             // [bf16(a) | bf16(b)<<16], 1 instr
  unsigned r;
  asm("v_cvt_pk_bf16_f32 %0, %1, %2" : "=v"(r) : "v"(a), "v"(b));
  return r;
}

// gfx950 permlane swaps: both operands are read+written.
// swap32: x' = [x.lanes0-31 | y.lanes0-31], y' = [x.lanes32-63 | y.lanes32-63]
DEV void swap32(unsigned &x, unsigned &y) {
  asm volatile("v_permlane32_swap_b32 %0, %1" : "+v"(x), "+v"(y));
}
// swap16 (rows = 16-lane groups): x' = [x.r0, y.r0, x.r2, y.r2], y' = [x.r1, y.r1, x.r3, y.r3]
DEV void swap16(unsigned &x, unsigned &y) {
  asm volatile("v_permlane16_swap_b32 %0, %1" : "+v"(x), "+v"(y));
}

typedef const __attribute__((address_space(1))) void* gas1_t;
typedef __attribute__((address_space(3))) void* las3_t;
DEV void gload16(const void* g, void* l) {
  // global -> LDS direct, 16B/lane; LDS dest = wave-uniform base + lane*16.
  __builtin_amdgcn_global_load_lds((gas1_t)g, (las3_t)l, 16, 0, 0);
}

DEV f32x4 mfma16(short8 a, short8 b, f32x4 c) {
  return __builtin_amdgcn_mfma_f32_16x16x32_bf16(a, b, c, 0, 0, 0);
}

// ---------------- prep kernels ----------------

__global__ __launch_bounds__(256) void convert_x_kernel(const float* __restrict__ x,
                                                        unsigned short* __restrict__ xb) {
  size_t i = ((size_t)blockIdx.x * 256 + threadIdx.x) * 4;
  float4 v = *(const float4*)(x + i);
  unsigned long long pack = (unsigned long long)f2bf(v.x)
                          | ((unsigned long long)f2bf(v.y) << 16)
                          | ((unsigned long long)f2bf(v.z) << 32)
                          | ((unsigned long long)f2bf(v.w) << 48);
  *(unsigned long long*)(xb + i) = pack;
}

// src [K][N] fp32 -> dst [N][K] bf16 (LDS tiled transpose, 64x64 tiles)
__global__ __launch_bounds__(256) void transpose_w_kernel(const float* __restrict__ src,
                                                          unsigned short* __restrict__ dst,
                                                          int K, int N) {
  __shared__ float tile[64][65];
  const int k0 = blockIdx.x * 64, n0 = blockIdx.y * 64;
  for (int i = threadIdx.x; i < 4096; i += 256) {
    int r = i >> 6, c = i & 63;
    tile[r][c] = src[(size_t)(k0 + r) * N + n0 + c];
  }
  __syncthreads();
  for (int i = threadIdx.x; i < 4096; i += 256) {
    int r = i >> 6, c = i & 63;
    dst[(size_t)(n0 + r) * K + k0 + c] = f2bf(tile[c][r]);
  }
}

__global__ __launch_bounds__(256) void rope_table_kernel(float2* __restrict__ tab) {
  int t = blockIdx.x * 256 + threadIdx.x;        // S*64 = 131072
  int s = t >> 6, i = t & 63;
  float freq = powf(10000.0f, -(float)i * (1.0f / 64.0f));
  float ang = (float)s * freq;
  tab[t] = make_float2(cosf(ang), sinf(ang));
}

// QKV [4096][3072] bf16 -> Qb [B][H][S][hd] (rope, *log2e/sqrt(hd)), Kb (rope)
__global__ __launch_bounds__(256) void rope_scatter_kernel(const unsigned short* __restrict__ QKV,
                                                           const float2* __restrict__ tab,
                                                           unsigned short* __restrict__ Qb,
                                                           unsigned short* __restrict__ Kb) {
  int t = blockIdx.x * 256 + threadIdx.x;
  const float qscale = 0.12751741161895452f;     // (1/sqrt(128)) * log2(e)
  if (t < (1 << 22)) {                           // Q pairs: B*S*H*64 = 2^22
    int i = t & 63, h = (t >> 6) & 15, s = (t >> 10) & 2047, b = t >> 21;
    const unsigned short* p = QKV + (size_t)(b * NS + s) * NQKV + h * HD + 2 * i;
    float2 cs = tab[s * 64 + i];
    float x1 = bf2f(p[0]), x2 = bf2f(p[1]);
    unsigned short* q = Qb + (size_t)((b * NH + h) * NS + s) * HD + 2 * i;
    q[0] = f2bf((x1 * cs.x - x2 * cs.y) * qscale);
    q[1] = f2bf((x1 * cs.y + x2 * cs.x) * qscale);
  } else {                                       // K pairs: B*S*KV*64 = 2^20
    int u = t - (1 << 22);
    int i = u & 63, kv = (u >> 6) & 3, s = (u >> 8) & 2047, b = u >> 19;
    const unsigned short* p = QKV + (size_t)(b * NS + s) * NQKV + 2048 + kv * HD + 2 * i;
    float2 cs = tab[s * 64 + i];
    float x1 = bf2f(p[0]), x2 = bf2f(p[1]);
    unsigned short* k = Kb + (size_t)((b * NKV + kv) * NS + s) * HD + 2 * i;
    k[0] = f2bf(x1 * cs.x - x2 * cs.y);
    k[1] = f2bf(x1 * cs.y + x2 * cs.x);
  }
}

// V columns of QKV -> Vt [B][KV][hd][S] bf16 (transposed for PV A-fragments)
__global__ __launch_bounds__(256) void transpose_v_kernel(const unsigned short* __restrict__ QKV,
                                                          unsigned short* __restrict__ Vt) {
  __shared__ unsigned short tile[64][65];
  const int bk = blockIdx.x, b = bk >> 2, kv = bk & 3;
  const int s0 = blockIdx.y * 64, d0 = blockIdx.z * 64;
  for (int i = threadIdx.x; i < 4096; i += 256) {
    int r = i >> 6, c = i & 63;   // r = s-offset, c = d-offset
    tile[r][c] = QKV[(size_t)(b * NS + s0 + r) * NQKV + 2560 + kv * HD + d0 + c];
  }
  __syncthreads();
  for (int i = threadIdx.x; i < 4096; i += 256) {
    int r = i >> 6, c = i & 63;   // r = d-offset, c = s-offset
    Vt[(size_t)((b * NKV + kv) * HD + d0 + r) * NS + s0 + c] = tile[c][r];
  }
}

// ---------------- GEMM: C[M][N] = A[M][K=2048] * Bt[N][K]^T, bf16 in, acc fp32 ----------------
// 128x128 tile, BK=32, 4 waves (2x2), m97 structure (global_load_lds staging).

template <int N, bool OUTBF16>
__global__ __launch_bounds__(256) void gemm_kernel(const unsigned short* __restrict__ A,
                                                   const unsigned short* __restrict__ Bt,
                                                   void* __restrict__ Cout) {
  __shared__ unsigned short As[128 * 32];  // 8 KB
  __shared__ unsigned short Bs[128 * 32];
  const int K = 2048;
  const int tid = threadIdx.x, wid = tid >> 6, lane = tid & 63;
  const int wm = wid >> 1, wn = wid & 1;
  const int m0 = blockIdx.x * 128, n0 = blockIdx.y * 128;
  f32x4 acc[4][4] = {};
  const int srow = tid >> 2;           // 0..63
  const int scol = (tid & 3) * 8;
  const unsigned short* Ab = A + (size_t)(m0 + srow) * K + scol;
  const unsigned short* Ab2 = Ab + (size_t)64 * K;
  const unsigned short* Bb = Bt + (size_t)(n0 + srow) * K + scol;
  const unsigned short* Bb2 = Bb + (size_t)64 * K;

  for (int kt = 0; kt < K; kt += 32) {
    gload16(Ab + kt, &As[wid * 512]);
    gload16(Ab2 + kt, &As[2048 + wid * 512]);
    gload16(Bb + kt, &Bs[wid * 512]);
    gload16(Bb2 + kt, &Bs[2048 + wid * 512]);
    __syncthreads();                   // drains vmcnt before use
    short8 af[4], bfr[4];
#pragma unroll
    for (int r = 0; r < 4; ++r)
      af[r] = *(const short8*)&As[(wm * 64 + r * 16 + (lane & 15)) * 32 + (lane >> 4) * 8];
#pragma unroll
    for (int c = 0; c < 4; ++c)
      bfr[c] = *(const short8*)&Bs[(wn * 64 + c * 16 + (lane & 15)) * 32 + (lane >> 4) * 8];
    __builtin_amdgcn_s_setprio(1);
#pragma unroll
    for (int r = 0; r < 4; ++r)
#pragma unroll
      for (int c = 0; c < 4; ++c)
        acc[r][c] = mfma16(af[r], bfr[c], acc[r][c]);
    __builtin_amdgcn_s_setprio(0);
    __syncthreads();
  }

  // epilogue: C row = m0 + wm*64 + r*16 + (lane>>4)*4 + j ; col = n0 + wn*64 + c*16 + (lane&15)
  if (OUTBF16) {
    unsigned short* C = (unsigned short*)Cout;
#pragma unroll
    for (int r = 0; r < 4; ++r) {
      const int row = m0 + wm * 64 + r * 16 + (lane >> 4) * 4;
#pragma unroll
      for (int c = 0; c < 4; ++c) {
        const int col = n0 + wn * 64 + c * 16 + (lane & 15);
#pragma unroll
        for (int j = 0; j < 4; ++j)
          C[(size_t)(row + j) * N + col] = f2bf(acc[r][c][j]);
      }
    }
  } else {
    float* C = (float*)Cout;
#pragma unroll
    for (int r = 0; r < 4; ++r) {
      const int row = m0 + wm * 64 + r * 16 + (lane >> 4) * 4;
#pragma unroll
      for (int c = 0; c < 4; ++c) {
        const int col = n0 + wn * 64 + c * 16 + (lane & 15);
#pragma unroll
        for (int j = 0; j < 4; ++j)
          C[(size_t)(row + j) * N + col] = acc[r][c][j];
      }
    }
  }
}

// ---------------- flash attention (non-causal, GQA) ----------------
// grid = B*H*(S/128) = 512 blocks; 4 waves, wave owns 32 q-rows (2 q-frags);
// KVBLK=64. K double-buffered in LDS (swz (row&7)<<3), staged via gload_lds.
// V read DIRECTLY from global Vt[d][s] (L1/L2-resident; issued under softmax).
// ONE barrier per iter: stage(next)->compute->__syncthreads().
// SWAPPED QK^T: s = mfma(K_frag, Q_frag) -> P[k][q], q = lane&15 fixed.
// P redistributed to PV B-frags in registers via permlane32/16 swaps (T12),
// packed with v_cvt_pk_bf16_f32.
// Scores in log2 units (Q pre-scaled by log2e/sqrt(hd)); softmax = exp2.
// Defer-max (T13): skip od-rescale unless a row max grows past THR=8.

__global__ __launch_bounds__(256, 2) void attn_kernel(const unsigned short* __restrict__ Qb,
                                                      const unsigned short* __restrict__ Kb,
                                                      const unsigned short* __restrict__ Vt,
                                                      unsigned short* __restrict__ O) {
  __shared__ unsigned short Ks[2][64 * 128];   // 32 KB
  const int tid = threadIdx.x, wid = tid >> 6, lane = tid & 63;
  const int blk = blockIdx.x;
  const int qt = blk & 15, h = (blk >> 4) & 15, b = blk >> 8;
  const int kvh = h >> 2;
  const int q0 = qt * 128 + wid * 32;

  const unsigned short* qhead = Qb + (size_t)((b * NH + h) * NS) * HD;
  const unsigned short* khead = Kb + (size_t)((b * NKV + kvh) * NS) * HD;
  const unsigned short* vhead = Vt + (size_t)((b * NKV + kvh) * HD) * NS;

  const int cl = lane & 15, g4 = (lane >> 4) * 4, hi8 = (lane >> 4) * 8;
  const int swk = (lane & 7) << 3;

  // stage one K tile (4 gload16 per wave) into buffer `buf`
  auto stageK = [&](int buf, int kt) {
#pragma unroll
    for (int i = 0; i < 4; ++i) {
      int row = i * 16 + (tid >> 4);
      int col = ((tid & 15) * 8) ^ ((row & 7) << 3);
      gload16(khead + (size_t)(kt + row) * HD + col, &Ks[buf][i * 2048 + wid * 512]);
    }
  };

  stageK(0, 0);   // prologue prefetch (in flight during qf loads)

  short8 qf[2][4];
#pragma unroll
  for (int r = 0; r < 2; ++r)
#pragma unroll
    for (int kk = 0; kk < 4; ++kk)
      qf[r][kk] = *(const short8*)(qhead + (size_t)(q0 + r * 16 + cl) * HD + kk * 32 + hi8);

  f32x4 od[2][8] = {};
  float mrun[2] = {-1e30f, -1e30f}, lpart[2] = {0.f, 0.f};

  __syncthreads();   // stage0 visible to all waves

  int cur = 0;
  for (int it = 0; it < NS / 64; ++it) {
    const int kt = it * 64;
    // ---- prefetch next K tile into the other buffer (read at it+1) ----
    if (it + 1 < NS / 64) stageK(cur ^ 1, kt + 64);

    const unsigned short* ks = Ks[cur];

    // ---- swapped QK^T: s[r][c4][j] = P[k = c4*16 + g4 + j][q = q0+16r+cl] ----
    f32x4 s[2][4];
#pragma unroll
    for (int r = 0; r < 2; ++r)
#pragma unroll
      for (int c4 = 0; c4 < 4; ++c4) s[r][c4] = f32x4{0.f, 0.f, 0.f, 0.f};
    __builtin_amdgcn_s_setprio(1);
#pragma unroll
    for (int c4 = 0; c4 < 4; ++c4)
#pragma unroll
      for (int kk = 0; kk < 4; ++kk) {
        short8 kf = *(const short8*)&ks[((c4 * 16 + cl) * 128 + kk * 32 + hi8) ^ swk];
        s[0][c4] = mfma16(kf, qf[0][kk], s[0][c4]);
        s[1][c4] = mfma16(kf, qf[1][kk], s[1][c4]);
      }
    __builtin_amdgcn_s_setprio(0);

    // ---- issue V fragment loads now (global, L1/L2); softmax hides latency ----
    short8 vfa[8], vfb[8];
#pragma unroll
    for (int c = 0; c < 8; ++c) {
      const unsigned short* vrow = vhead + (size_t)(c * 16 + cl) * NS + kt + hi8;
      vfa[c] = *(const short8*)(vrow);
      vfb[c] = *(const short8*)(vrow + 32);
    }

    // ---- online softmax (log2 domain): k is lane-local, q = cl fixed ----
    float mt[2];
#pragma unroll
    for (int r = 0; r < 2; ++r) {
      float m = fmaxf(fmaxf(fmaxf(s[r][0][0], s[r][0][1]), fmaxf(s[r][0][2], s[r][0][3])),
                      fmaxf(fmaxf(s[r][1][0], s[r][1][1]), fmaxf(s[r][1][2], s[r][1][3])));
      float m2 = fmaxf(fmaxf(fmaxf(s[r][2][0], s[r][2][1]), fmaxf(s[r][2][2], s[r][2][3])),
                       fmaxf(fmaxf(s[r][3][0], s[r][3][1]), fmaxf(s[r][3][2], s[r][3][3])));
      m = fmaxf(m, m2);
      m = fmaxf(m, __shfl_xor(m, 16, 64));
      m = fmaxf(m, __shfl_xor(m, 32, 64));
      mt[r] = m;
    }
    bool need = (mt[0] > mrun[0] + 8.0f) || (mt[1] > mrun[1] + 8.0f);
    if (__any(need)) {
#pragma unroll
      for (int r = 0; r < 2; ++r) {
        float mn = fmaxf(mrun[r], mt[r]);
        float corr = __builtin_amdgcn_exp2f(mrun[r] - mn);
        mrun[r] = mn;
        lpart[r] *= corr;
#pragma unroll
        for (int c = 0; c < 8; ++c)
          od[r][c] *= corr;
      }
    }
#pragma unroll
    for (int r = 0; r < 2; ++r) {
      float acc = 0.f;
#pragma unroll
      for (int c4 = 0; c4 < 4; ++c4)
#pragma unroll
        for (int j = 0; j < 4; ++j) {
          float p = __builtin_amdgcn_exp2f(s[r][c4][j] - mrun[r]);
          s[r][c4][j] = p;
          acc += p;
        }
      lpart[r] += acc;
    }

    // ---- pack P to bf16 pairs (cvt_pk) and redistribute to PV B-frags ----
    short8 pb[2][2];
#pragma unroll
    for (int r = 0; r < 2; ++r) {
      unsigned w00 = cvtpk(s[r][0][0], s[r][0][1]), w01 = cvtpk(s[r][0][2], s[r][0][3]);
      unsigned w10 = cvtpk(s[r][1][0], s[r][1][1]), w11 = cvtpk(s[r][1][2], s[r][1][3]);
      unsigned w20 = cvtpk(s[r][2][0], s[r][2][1]), w21 = cvtpk(s[r][2][2], s[r][2][3]);
      unsigned w30 = cvtpk(s[r][3][0], s[r][3][1]), w31 = cvtpk(s[r][3][2], s[r][3][3]);
      union { unsigned u[4]; short8 v; } t0, t1;
      swap32(w00, w10); swap16(w00, w10); t0.u[0] = w00; t0.u[2] = w10;
      swap32(w01, w11); swap16(w01, w11); t0.u[1] = w01; t0.u[3] = w11;
      swap32(w20, w30); swap16(w20, w30); t1.u[0] = w20; t1.u[2] = w30;
      swap32(w21, w31); swap16(w21, w31); t1.u[1] = w21; t1.u[3] = w31;
      pb[r][0] = t0.v;   // k 0..31
      pb[r][1] = t1.v;   // k 32..63
    }

    // ---- PV (swapped): od[r][c] += V^T-block(c) @ P-frag ----
    __builtin_amdgcn_s_setprio(1);
#pragma unroll
    for (int c = 0; c < 8; ++c) {
      od[0][c] = mfma16(vfa[c], pb[0][0], od[0][c]);
      od[0][c] = mfma16(vfb[c], pb[0][1], od[0][c]);
      od[1][c] = mfma16(vfa[c], pb[1][0], od[1][c]);
      od[1][c] = mfma16(vfb[c], pb[1][1], od[1][c]);
    }
    __builtin_amdgcn_s_setprio(0);

    // one barrier per iter: drains this wave's staged loads (issued ~whole
    // iter ago) and rendezvous — next iter's reads of Ks[cur^1] are safe.
    __syncthreads();
    cur ^= 1;
  }

  // ---- finalize: cross-group l-sum + packed 8B stores ----
  float linv[2];
#pragma unroll
  for (int r = 0; r < 2; ++r) {
    float l = lpart[r];
    l += __shfl_xor(l, 16, 64);
    l += __shfl_xor(l, 32, 64);
    linv[r] = 1.0f / l;
  }
#pragma unroll
  for (int r = 0; r < 2; ++r) {
    const size_t row = (size_t)(b * NS + q0 + 16 * r + cl);
#pragma unroll
    for (int c = 0; c < 8; ++c) {
      uint2 pk;
      pk.x = pack2bf_rne(od[r][c][0] * linv[r], od[r][c][1] * linv[r]);
      pk.y = pack2bf_rne(od[r][c][2] * linv[r], od[r][c][3] * linv[r]);
      *(uint2*)(O + row * ND + h * HD + c * 16 + g4) = pk;
    }
  }
}

// ---------------- launch ----------------

extern "C" void kernel_launch(void* const* d_in, const int* in_sizes, int n_in,
                              void* d_out, int out_size, void* d_ws, size_t ws_size,
                              hipStream_t stream) {
  const float* x  = (const float*)d_in[0];
  const float* wq = (const float*)d_in[1];
  const float* wk = (const float*)d_in[2];
  const float* wv = (const float*)d_in[3];
  const float* wo = (const float*)d_in[4];
  float* out = (float*)d_out;
  char* ws = (char*)d_ws;

  // ws layout (bytes); total needed = 63,963,136
  unsigned short* xb   = (unsigned short*)(ws + 0);          // 16.8 MB [4096][2048] bf16
  unsigned short* wT   = (unsigned short*)(ws + 16777216);   // 12.6 MB [3072][2048] bf16 (wq|wk|wv)^T
  unsigned short* woT  = (unsigned short*)(ws + 29360128);   //  8.4 MB [2048][2048] bf16
  float2*         tab  = (float2*)(ws + 37748736);           //  1.0 MB [2048][64] cos/sin
  unsigned short* QKV  = (unsigned short*)(ws + 38797312);   // 25.2 MB [4096][3072] bf16
  unsigned short* Qb   = xb;                                 // alias: xb dead after GEMM1
  unsigned short* Kb   = wT;                                 // alias: wT dead after GEMM1
  unsigned short* Vt   = (unsigned short*)(ws + 16777216 + 4194304);
  unsigned short* Obuf = QKV;                                // alias: QKV dead after scatter

  convert_x_kernel<<<8192, 256, 0, stream>>>(x, xb);
  transpose_w_kernel<<<dim3(32, 32), 256, 0, stream>>>(wq, wT, 2048, 2048);
  transpose_w_kernel<<<dim3(32, 8),  256, 0, stream>>>(wk, wT + (size_t)2048 * 2048, 2048, 512);
  transpose_w_kernel<<<dim3(32, 8),  256, 0, stream>>>(wv, wT + (size_t)2560 * 2048, 2048, 512);
  transpose_w_kernel<<<dim3(32, 32), 256, 0, stream>>>(wo, woT, 2048, 2048);
  rope_table_kernel<<<512, 256, 0, stream>>>(tab);

  gemm_kernel<NQKV, true><<<dim3(32, 24), 256, 0, stream>>>(xb, wT, QKV);

  rope_scatter_kernel<<<20480, 256, 0, stream>>>(QKV, tab, Qb, Kb);
  transpose_v_kernel<<<dim3(8, 32, 2), 256, 0, stream>>>(QKV, Vt);

  attn_kernel<<<512, 256, 0, stream>>>(Qb, Kb, Vt, Obuf);

  gemm_kernel<ND, false><<<dim3(32, 16), 256, 0, stream>>>(Obuf, woT, out);
}

// Round 6
// 240.774 us; speedup vs baseline: 1.2113x; 1.2113x over previous
//
#include <hip/hip_runtime.h>

// ---------------------------------------------------------------------------
// MHA (GQA + RoPE, non-causal) on MI355X, bf16 MFMA pipeline, fp32 in/out.
// B=2 S=2048 D=2048 H=16 KV=4 hd=128.
// R6: attention reverted to R4 structure (V in LDS, counted vmcnt(8)) —
//     R5's direct-global V poisoned the vmcnt queue (in-order counter forced
//     draining the K prefetch). Keep cvt_pk packing from R5.
//     GEMM: BK=64 (half the barrier drains), T2 XOR-swizzled LDS (pre-swizzled
//     gload_lds source + swizzled reads), T1 XCD-aware block swizzle.
// ---------------------------------------------------------------------------

typedef __attribute__((ext_vector_type(8))) short short8;
typedef __attribute__((ext_vector_type(4))) float f32x4;

#define DEV static __device__ __forceinline__

#define NB 2
#define NS 2048
#define ND 2048
#define NH 16
#define NKV 4
#define HD 128
#define NQKV 3072   // H*hd + 2*KV*hd

DEV unsigned short f2bf(float f) {
  union { float f; unsigned u; } v; v.f = f;
  unsigned r = v.u + 0x7fffu + ((v.u >> 16) & 1u);   // RNE
  return (unsigned short)(r >> 16);
}
DEV float bf2f(unsigned short u) {
  union { unsigned u; float f; } v; v.u = ((unsigned)u) << 16; return v.f;
}
DEV unsigned pack2bf_rne(float a, float b) {
  return (unsigned)f2bf(a) | ((unsigned)f2bf(b) << 16);
}
DEV unsigned cvtpk(float a, float b) {             // [bf16(a) | bf16(b)<<16], 1 instr
  unsigned r;
  asm("v_cvt_pk_bf16_f32 %0, %1, %2" : "=v"(r) : "v"(a), "v"(b));
  return r;
}

// gfx950 permlane swaps: both operands are read+written.
DEV void swap32(unsigned &x, unsigned &y) {
  asm volatile("v_permlane32_swap_b32 %0, %1" : "+v"(x), "+v"(y));
}
DEV void swap16(unsigned &x, unsigned &y) {
  asm volatile("v_permlane16_swap_b32 %0, %1" : "+v"(x), "+v"(y));
}

typedef const __attribute__((address_space(1))) void* gas1_t;
typedef __attribute__((address_space(3))) void* las3_t;
DEV void gload16(const void* g, void* l) {
  __builtin_amdgcn_global_load_lds((gas1_t)g, (las3_t)l, 16, 0, 0);
}

DEV f32x4 mfma16(short8 a, short8 b, f32x4 c) {
  return __builtin_amdgcn_mfma_f32_16x16x32_bf16(a, b, c, 0, 0, 0);
}

// ---------------- prep kernels ----------------

__global__ __launch_bounds__(256) void convert_x_kernel(const float* __restrict__ x,
                                                        unsigned short* __restrict__ xb) {
  size_t i = ((size_t)blockIdx.x * 256 + threadIdx.x) * 4;
  float4 v = *(const float4*)(x + i);
  unsigned long long pack = (unsigned long long)f2bf(v.x)
                          | ((unsigned long long)f2bf(v.y) << 16)
                          | ((unsigned long long)f2bf(v.z) << 32)
                          | ((unsigned long long)f2bf(v.w) << 48);
  *(unsigned long long*)(xb + i) = pack;
}

// src [K][N] fp32 -> dst [N][K] bf16 (LDS tiled transpose, 64x64 tiles)
__global__ __launch_bounds__(256) void transpose_w_kernel(const float* __restrict__ src,
                                                          unsigned short* __restrict__ dst,
                                                          int K, int N) {
  __shared__ float tile[64][65];
  const int k0 = blockIdx.x * 64, n0 = blockIdx.y * 64;
  for (int i = threadIdx.x; i < 4096; i += 256) {
    int r = i >> 6, c = i & 63;
    tile[r][c] = src[(size_t)(k0 + r) * N + n0 + c];
  }
  __syncthreads();
  for (int i = threadIdx.x; i < 4096; i += 256) {
    int r = i >> 6, c = i & 63;
    dst[(size_t)(n0 + r) * K + k0 + c] = f2bf(tile[c][r]);
  }
}

__global__ __launch_bounds__(256) void rope_table_kernel(float2* __restrict__ tab) {
  int t = blockIdx.x * 256 + threadIdx.x;        // S*64 = 131072
  int s = t >> 6, i = t & 63;
  float freq = powf(10000.0f, -(float)i * (1.0f / 64.0f));
  float ang = (float)s * freq;
  tab[t] = make_float2(cosf(ang), sinf(ang));
}

// QKV [4096][3072] bf16 -> Qb [B][H][S][hd] (rope, *log2e/sqrt(hd)), Kb (rope)
__global__ __launch_bounds__(256) void rope_scatter_kernel(const unsigned short* __restrict__ QKV,
                                                           const float2* __restrict__ tab,
                                                           unsigned short* __restrict__ Qb,
                                                           unsigned short* __restrict__ Kb) {
  int t = blockIdx.x * 256 + threadIdx.x;
  const float qscale = 0.12751741161895452f;     // (1/sqrt(128)) * log2(e)
  if (t < (1 << 22)) {                           // Q pairs: B*S*H*64 = 2^22
    int i = t & 63, h = (t >> 6) & 15, s = (t >> 10) & 2047, b = t >> 21;
    const unsigned short* p = QKV + (size_t)(b * NS + s) * NQKV + h * HD + 2 * i;
    float2 cs = tab[s * 64 + i];
    float x1 = bf2f(p[0]), x2 = bf2f(p[1]);
    unsigned short* q = Qb + (size_t)((b * NH + h) * NS + s) * HD + 2 * i;
    q[0] = f2bf((x1 * cs.x - x2 * cs.y) * qscale);
    q[1] = f2bf((x1 * cs.y + x2 * cs.x) * qscale);
  } else {                                       // K pairs: B*S*KV*64 = 2^20
    int u = t - (1 << 22);
    int i = u & 63, kv = (u >> 6) & 3, s = (u >> 8) & 2047, b = u >> 19;
    const unsigned short* p = QKV + (size_t)(b * NS + s) * NQKV + 2048 + kv * HD + 2 * i;
    float2 cs = tab[s * 64 + i];
    float x1 = bf2f(p[0]), x2 = bf2f(p[1]);
    unsigned short* k = Kb + (size_t)((b * NKV + kv) * NS + s) * HD + 2 * i;
    k[0] = f2bf(x1 * cs.x - x2 * cs.y);
    k[1] = f2bf(x1 * cs.y + x2 * cs.x);
  }
}

// V columns of QKV -> Vt [B][KV][hd][S] bf16 (transposed for PV A-fragments)
__global__ __launch_bounds__(256) void transpose_v_kernel(const unsigned short* __restrict__ QKV,
                                                          unsigned short* __restrict__ Vt) {
  __shared__ unsigned short tile[64][65];
  const int bk = blockIdx.x, b = bk >> 2, kv = bk & 3;
  const int s0 = blockIdx.y * 64, d0 = blockIdx.z * 64;
  for (int i = threadIdx.x; i < 4096; i += 256) {
    int r = i >> 6, c = i & 63;   // r = s-offset, c = d-offset
    tile[r][c] = QKV[(size_t)(b * NS + s0 + r) * NQKV + 2560 + kv * HD + d0 + c];
  }
  __syncthreads();
  for (int i = threadIdx.x; i < 4096; i += 256) {
    int r = i >> 6, c = i & 63;   // r = d-offset, c = s-offset
    Vt[(size_t)((b * NKV + kv) * HD + d0 + r) * NS + s0 + c] = tile[c][r];
  }
}

// ---------------- GEMM: C[M][N] = A[M][K=2048] * Bt[N][K]^T, bf16 in, acc fp32 ----------------
// 128x128 tile, BK=64, 4 waves (2x2). T2 XOR-swizzled LDS ((row&7)<<3 elems,
// pre-swizzled gload_lds source), T1 XCD block swizzle. m97-style drain sync.

template <int N, bool OUTBF16>
__global__ __launch_bounds__(256) void gemm_kernel(const unsigned short* __restrict__ A,
                                                   const unsigned short* __restrict__ Bt,
                                                   void* __restrict__ Cout) {
  __shared__ unsigned short As[128 * 64];  // 16 KB
  __shared__ unsigned short Bs[128 * 64];  // 16 KB
  const int K = 2048;
  const int tid = threadIdx.x, wid = tid >> 6, lane = tid & 63;
  const int wm = wid >> 1, wn = wid & 1;

  // T1: XCD-aware bijective block swizzle (nwg % 8 == 0 for both GEMMs)
  const int nwg = gridDim.x * gridDim.y;
  const int bid = blockIdx.y * gridDim.x + blockIdx.x;
  const int swzb = (bid & 7) * (nwg >> 3) + (bid >> 3);
  const int m0 = (swzb % gridDim.x) * 128;
  const int n0 = (swzb / gridDim.x) * 128;

  f32x4 acc[4][4] = {};
  const int cl = lane & 15, hi8 = (lane >> 4) * 8;
  const int swg = (cl & 7) << 3;                 // read-side XOR swizzle (elems)

  // staging: round i covers rows i*32..i*32+31; thread -> row wid*8 + (lane>>3),
  // col (lane&7)*8, source col XOR'd so linear LDS == swizzled layout.
  const int srow = lane >> 3;                    // 0..7, == row&7
  const int scol = ((lane & 7) * 8) ^ (srow << 3);
  const unsigned short* PA = A + (size_t)(m0 + wid * 8 + srow) * K + scol;
  const unsigned short* PB = Bt + (size_t)(n0 + wid * 8 + srow) * K + scol;

  for (int kt = 0; kt < K; kt += 64) {
#pragma unroll
    for (int i = 0; i < 4; ++i)
      gload16(PA + (size_t)(i * 32) * K + kt, &As[i * 2048 + wid * 512]);
#pragma unroll
    for (int i = 0; i < 4; ++i)
      gload16(PB + (size_t)(i * 32) * K + kt, &Bs[i * 2048 + wid * 512]);
    __syncthreads();                   // drains vmcnt before use

    short8 af[2][4], bfr[2][4];
#pragma unroll
    for (int kk = 0; kk < 2; ++kk) {
#pragma unroll
      for (int r = 0; r < 4; ++r)
        af[kk][r] = *(const short8*)&As[(wm * 64 + r * 16 + cl) * 64 + ((kk * 32 + hi8) ^ swg)];
#pragma unroll
      for (int c = 0; c < 4; ++c)
        bfr[kk][c] = *(const short8*)&Bs[(wn * 64 + c * 16 + cl) * 64 + ((kk * 32 + hi8) ^ swg)];
    }
    __builtin_amdgcn_s_setprio(1);
#pragma unroll
    for (int kk = 0; kk < 2; ++kk)
#pragma unroll
      for (int r = 0; r < 4; ++r)
#pragma unroll
        for (int c = 0; c < 4; ++c)
          acc[r][c] = mfma16(af[kk][r], bfr[kk][c], acc[r][c]);
    __builtin_amdgcn_s_setprio(0);
    __syncthreads();
  }

  // epilogue: C row = m0 + wm*64 + r*16 + (lane>>4)*4 + j ; col = n0 + wn*64 + c*16 + cl
  if (OUTBF16) {
    unsigned short* C = (unsigned short*)Cout;
#pragma unroll
    for (int r = 0; r < 4; ++r) {
      const int row = m0 + wm * 64 + r * 16 + (lane >> 4) * 4;
#pragma unroll
      for (int c = 0; c < 4; ++c) {
        const int col = n0 + wn * 64 + c * 16 + cl;
#pragma unroll
        for (int j = 0; j < 4; ++j)
          C[(size_t)(row + j) * N + col] = f2bf(acc[r][c][j]);
      }
    }
  } else {
    float* C = (float*)Cout;
#pragma unroll
    for (int r = 0; r < 4; ++r) {
      const int row = m0 + wm * 64 + r * 16 + (lane >> 4) * 4;
#pragma unroll
      for (int c = 0; c < 4; ++c) {
        const int col = n0 + wn * 64 + c * 16 + cl;
#pragma unroll
        for (int j = 0; j < 4; ++j)
          C[(size_t)(row + j) * N + col] = acc[r][c][j];
      }
    }
  }
}

// ---------------- flash attention (non-causal, GQA) ----------------
// R4 proven structure: grid = 512 blocks; 4 waves, 32 q-rows/wave (2 q-frags);
// KVBLK=64, K+V double-buffered in LDS, counted vmcnt(8) prefetch, 2 barriers.
// SWAPPED QK^T -> P[k][q] lane-local; in-register P redistribution
// (cvt_pk + permlane32/16 swaps). Scores in log2 units; softmax = exp2.
// Defer-max (T13) THR=8.

__global__ __launch_bounds__(256, 2) void attn_kernel(const unsigned short* __restrict__ Qb,
                                                      const unsigned short* __restrict__ Kb,
                                                      const unsigned short* __restrict__ Vt,
                                                      unsigned short* __restrict__ O) {
  __shared__ unsigned short Ks[2][64 * 128];   // 32 KB
  __shared__ unsigned short Vs[2][128 * 64];   // 32 KB
  const int tid = threadIdx.x, wid = tid >> 6, lane = tid & 63;
  const int blk = blockIdx.x;
  const int qt = blk & 15, h = (blk >> 4) & 15, b = blk >> 8;
  const int kvh = h >> 2;
  const int q0 = qt * 128 + wid * 32;

  const unsigned short* qhead = Qb + (size_t)((b * NH + h) * NS) * HD;
  const unsigned short* khead = Kb + (size_t)((b * NKV + kvh) * NS) * HD;
  const unsigned short* vhead = Vt + (size_t)((b * NKV + kvh) * HD) * NS;

  const int cl = lane & 15, g4 = (lane >> 4) * 4, hi8 = (lane >> 4) * 8;
  const int swk = (lane & 7) << 3;

  auto stageKV = [&](int buf, int kt) {
#pragma unroll
    for (int i = 0; i < 4; ++i) {
      int row = i * 16 + (tid >> 4);
      int col = ((tid & 15) * 8) ^ ((row & 7) << 3);
      gload16(khead + (size_t)(kt + row) * HD + col, &Ks[buf][i * 2048 + wid * 512]);
    }
#pragma unroll
    for (int i = 0; i < 4; ++i) {
      int row = i * 32 + (tid >> 3);
      int col = ((tid & 7) * 8) ^ ((row & 7) << 3);
      gload16(vhead + (size_t)row * NS + kt + col, &Vs[buf][i * 2048 + wid * 512]);
    }
  };

  stageKV(0, 0);   // prologue prefetch (in flight during qf loads)

  short8 qf[2][4];
#pragma unroll
  for (int r = 0; r < 2; ++r)
#pragma unroll
    for (int kk = 0; kk < 4; ++kk)
      qf[r][kk] = *(const short8*)(qhead + (size_t)(q0 + r * 16 + cl) * HD + kk * 32 + hi8);

  f32x4 od[2][8] = {};
  float mrun[2] = {-1e30f, -1e30f}, lpart[2] = {0.f, 0.f};

  int cur = 0;
  for (int it = 0; it < NS / 64; ++it) {
    // prefetch next tile, then wait only for the CURRENT tile's 8 loads
    if (it + 1 < NS / 64) {
      stageKV(cur ^ 1, (it + 1) * 64);
      asm volatile("s_waitcnt vmcnt(8)" ::: "memory");
    } else {
      asm volatile("s_waitcnt vmcnt(0)" ::: "memory");
    }
    __builtin_amdgcn_s_barrier();      // current tile visible to all waves

    const unsigned short* ks = Ks[cur];
    const unsigned short* vs = Vs[cur];

    // ---- swapped QK^T: s[r][c4][j] = P[k = c4*16 + g4 + j][q = q0+16r+cl] ----
    f32x4 s[2][4];
#pragma unroll
    for (int r = 0; r < 2; ++r)
#pragma unroll
      for (int c4 = 0; c4 < 4; ++c4) s[r][c4] = f32x4{0.f, 0.f, 0.f, 0.f};
    __builtin_amdgcn_s_setprio(1);
#pragma unroll
    for (int c4 = 0; c4 < 4; ++c4)
#pragma unroll
      for (int kk = 0; kk < 4; ++kk) {
        short8 kf = *(const short8*)&ks[((c4 * 16 + cl) * 128 + kk * 32 + hi8) ^ swk];
        s[0][c4] = mfma16(kf, qf[0][kk], s[0][c4]);
        s[1][c4] = mfma16(kf, qf[1][kk], s[1][c4]);
      }
    __builtin_amdgcn_s_setprio(0);

    // ---- online softmax (log2 domain): k is lane-local, q = cl fixed ----
    float mt[2];
#pragma unroll
    for (int r = 0; r < 2; ++r) {
      float m = fmaxf(fmaxf(fmaxf(s[r][0][0], s[r][0][1]), fmaxf(s[r][0][2], s[r][0][3])),
                      fmaxf(fmaxf(s[r][1][0], s[r][1][1]), fmaxf(s[r][1][2], s[r][1][3])));
      float m2 = fmaxf(fmaxf(fmaxf(s[r][2][0], s[r][2][1]), fmaxf(s[r][2][2], s[r][2][3])),
                       fmaxf(fmaxf(s[r][3][0], s[r][3][1]), fmaxf(s[r][3][2], s[r][3][3])));
      m = fmaxf(m, m2);
      m = fmaxf(m, __shfl_xor(m, 16, 64));
      m = fmaxf(m, __shfl_xor(m, 32, 64));
      mt[r] = m;
    }
    bool need = (mt[0] > mrun[0] + 8.0f) || (mt[1] > mrun[1] + 8.0f);
    if (__any(need)) {
#pragma unroll
      for (int r = 0; r < 2; ++r) {
        float mn = fmaxf(mrun[r], mt[r]);
        float corr = __builtin_amdgcn_exp2f(mrun[r] - mn);
        mrun[r] = mn;
        lpart[r] *= corr;
#pragma unroll
        for (int c = 0; c < 8; ++c)
          od[r][c] *= corr;
      }
    }
#pragma unroll
    for (int r = 0; r < 2; ++r) {
      float acc = 0.f;
#pragma unroll
      for (int c4 = 0; c4 < 4; ++c4)
#pragma unroll
        for (int j = 0; j < 4; ++j) {
          float p = __builtin_amdgcn_exp2f(s[r][c4][j] - mrun[r]);
          s[r][c4][j] = p;
          acc += p;
        }
      lpart[r] += acc;
    }

    // ---- pack P to bf16 pairs (cvt_pk) and redistribute to PV B-frags ----
    short8 pb[2][2];
#pragma unroll
    for (int r = 0; r < 2; ++r) {
      unsigned w00 = cvtpk(s[r][0][0], s[r][0][1]), w01 = cvtpk(s[r][0][2], s[r][0][3]);
      unsigned w10 = cvtpk(s[r][1][0], s[r][1][1]), w11 = cvtpk(s[r][1][2], s[r][1][3]);
      unsigned w20 = cvtpk(s[r][2][0], s[r][2][1]), w21 = cvtpk(s[r][2][2], s[r][2][3]);
      unsigned w30 = cvtpk(s[r][3][0], s[r][3][1]), w31 = cvtpk(s[r][3][2], s[r][3][3]);
      union { unsigned u[4]; short8 v; } t0, t1;
      swap32(w00, w10); swap16(w00, w10); t0.u[0] = w00; t0.u[2] = w10;
      swap32(w01, w11); swap16(w01, w11); t0.u[1] = w01; t0.u[3] = w11;
      swap32(w20, w30); swap16(w20, w30); t1.u[0] = w20; t1.u[2] = w30;
      swap32(w21, w31); swap16(w21, w31); t1.u[1] = w21; t1.u[3] = w31;
      pb[r][0] = t0.v;   // k 0..31
      pb[r][1] = t1.v;   // k 32..63
    }

    // ---- PV (swapped): od[r][c] += V^T-block(c) @ P-frag; V frags shared ----
    __builtin_amdgcn_s_setprio(1);
#pragma unroll
    for (int c = 0; c < 8; ++c) {
      const int rr = c * 16 + cl;   // d-row in Vs
      short8 vf0 = *(const short8*)&vs[(rr * 64 + hi8) ^ swk];
      short8 vf1 = *(const short8*)&vs[(rr * 64 + 32 + hi8) ^ swk];
      od[0][c] = mfma16(vf0, pb[0][0], od[0][c]);
      od[0][c] = mfma16(vf1, pb[0][1], od[0][c]);
      od[1][c] = mfma16(vf0, pb[1][0], od[1][c]);
      od[1][c] = mfma16(vf1, pb[1][1], od[1][c]);
    }
    __builtin_amdgcn_s_setprio(0);
    __builtin_amdgcn_s_barrier();      // all waves done reading cur before overwrite
    cur ^= 1;
  }

  // ---- finalize: cross-group l-sum + packed 8B stores ----
  float linv[2];
#pragma unroll
  for (int r = 0; r < 2; ++r) {
    float l = lpart[r];
    l += __shfl_xor(l, 16, 64);
    l += __shfl_xor(l, 32, 64);
    linv[r] = 1.0f / l;
  }
#pragma unroll
  for (int r = 0; r < 2; ++r) {
    const size_t row = (size_t)(b * NS + q0 + 16 * r + cl);
#pragma unroll
    for (int c = 0; c < 8; ++c) {
      uint2 pk;
      pk.x = pack2bf_rne(od[r][c][0] * linv[r], od[r][c][1] * linv[r]);
      pk.y = pack2bf_rne(od[r][c][2] * linv[r], od[r][c][3] * linv[r]);
      *(uint2*)(O + row * ND + h * HD + c * 16 + g4) = pk;
    }
  }
}

// ---------------- launch ----------------

extern "C" void kernel_launch(void* const* d_in, const int* in_sizes, int n_in,
                              void* d_out, int out_size, void* d_ws, size_t ws_size,
                              hipStream_t stream) {
  const float* x  = (const float*)d_in[0];
  const float* wq = (const float*)d_in[1];
  const float* wk = (const float*)d_in[2];
  const float* wv = (const float*)d_in[3];
  const float* wo = (const float*)d_in[4];
  float* out = (float*)d_out;
  char* ws = (char*)d_ws;

  // ws layout (bytes); total needed = 63,963,136
  unsigned short* xb   = (unsigned short*)(ws + 0);          // 16.8 MB [4096][2048] bf16
  unsigned short* wT   = (unsigned short*)(ws + 16777216);   // 12.6 MB [3072][2048] bf16 (wq|wk|wv)^T
  unsigned short* woT  = (unsigned short*)(ws + 29360128);   //  8.4 MB [2048][2048] bf16
  float2*         tab  = (float2*)(ws + 37748736);           //  1.0 MB [2048][64] cos/sin
  unsigned short* QKV  = (unsigned short*)(ws + 38797312);   // 25.2 MB [4096][3072] bf16
  unsigned short* Qb   = xb;                                 // alias: xb dead after GEMM1
  unsigned short* Kb   = wT;                                 // alias: wT dead after GEMM1
  unsigned short* Vt   = (unsigned short*)(ws + 16777216 + 4194304);
  unsigned short* Obuf = QKV;                                // alias: QKV dead after scatter

  convert_x_kernel<<<8192, 256, 0, stream>>>(x, xb);
  transpose_w_kernel<<<dim3(32, 32), 256, 0, stream>>>(wq, wT, 2048, 2048);
  transpose_w_kernel<<<dim3(32, 8),  256, 0, stream>>>(wk, wT + (size_t)2048 * 2048, 2048, 512);
  transpose_w_kernel<<<dim3(32, 8),  256, 0, stream>>>(wv, wT + (size_t)2560 * 2048, 2048, 512);
  transpose_w_kernel<<<dim3(32, 32), 256, 0, stream>>>(wo, woT, 2048, 2048);
  rope_table_kernel<<<512, 256, 0, stream>>>(tab);

  gemm_kernel<NQKV, true><<<dim3(32, 24), 256, 0, stream>>>(xb, wT, QKV);

  rope_scatter_kernel<<<20480, 256, 0, stream>>>(QKV, tab, Qb, Kb);
  transpose_v_kernel<<<dim3(8, 32, 2), 256, 0, stream>>>(QKV, Vt);

  attn_kernel<<<512, 256, 0, stream>>>(Qb, Kb, Vt, Obuf);

  gemm_kernel<ND, false><<<dim3(32, 16), 256, 0, stream>>>(Obuf, woT, out);
}